// Round 19
// baseline (439.954 us; speedup 1.0000x reference)
//
#include <hip/hip_runtime.h>
#include <hip/hip_bf16.h>
#include <stdint.h>

typedef __hip_bfloat16 bf16;
typedef __attribute__((ext_vector_type(8))) short bf16x8;
typedef __attribute__((ext_vector_type(4))) float f32x4;

#define DEVFN static __device__ __forceinline__

DEVFN void gll16(const bf16* g, bf16* l) {
  __builtin_amdgcn_global_load_lds((const __attribute__((address_space(1))) void*)g,
                                   (__attribute__((address_space(3))) void*)l, 16, 0, 0);
}

DEVFN bf16 f2bf(float f) { return __float2bfloat16(f); }
DEVFN float b2f(unsigned short u) { return __bfloat162float(__builtin_bit_cast(bf16, u)); }

// ---------------- cast / transpose ----------------

__global__ __launch_bounds__(256) void cast_bf16_kernel(const float* __restrict__ in,
                                                        bf16* __restrict__ out, int n4) {
  int i = blockIdx.x * 256 + threadIdx.x;
  if (i >= n4) return;
  float4 v = ((const float4*)in)[i];
  ushort4 o;
  o.x = __builtin_bit_cast(unsigned short, f2bf(v.x));
  o.y = __builtin_bit_cast(unsigned short, f2bf(v.y));
  o.z = __builtin_bit_cast(unsigned short, f2bf(v.z));
  o.w = __builtin_bit_cast(unsigned short, f2bf(v.w));
  ((ushort4*)out)[i] = o;
}

DEVFN void tile_transpose(const float* __restrict__ in, bf16* __restrict__ out,
                          int R, int C, int r0, int c0) {
  __shared__ bf16 tile[32][33];
  for (int i = threadIdx.y; i < 32; i += 8)
    tile[i][threadIdx.x] = f2bf(in[(long)(r0 + i) * C + (c0 + threadIdx.x)]);
  __syncthreads();
  for (int i = threadIdx.y; i < 32; i += 8)
    out[(long)(c0 + i) * R + (r0 + threadIdx.x)] = tile[threadIdx.x][i];
}

// All 8 expert weight mats in one launch: z = e*2 + {0:ew1, 1:ew2}; 4096 tiles each.
__global__ __launch_bounds__(256) void w_experts_kernel(
    const float* __restrict__ ew1, const float* __restrict__ ew2,
    bf16* __restrict__ EW1T, bf16* __restrict__ EW2T) {
  const int z = blockIdx.y, e = z >> 1;
  const float* in;
  bf16* out;
  int R, C, TC;
  if ((z & 1) == 0) { in = ew1 + (long)e * 1024 * 4096; out = EW1T + (long)e * 4096 * 1024; R = 1024; C = 4096; TC = 128; }
  else              { in = ew2 + (long)e * 4096 * 1024; out = EW2T + (long)e * 1024 * 4096; R = 4096; C = 1024; TC = 32; }
  int flat = blockIdx.x;
  int tr = flat / TC, tc = flat - tr * TC;
  tile_transpose(in, out, R, C, tr * 32, tc * 32);
}

// Wq/Wk/Wv/Wo (all 1024x1024) in one launch: z picks matrix; 1024 tiles each.
__global__ __launch_bounds__(256) void w_qkvo_kernel(
    const float* __restrict__ Wq, const float* __restrict__ Wk,
    const float* __restrict__ Wv, const float* __restrict__ Wo,
    bf16* __restrict__ WQKVT, bf16* __restrict__ WOT) {
  const int z = blockIdx.y;
  const float* in = z == 0 ? Wq : z == 1 ? Wk : z == 2 ? Wv : Wo;
  bf16* out = z == 3 ? WOT : WQKVT + (long)z * 1024 * 1024;
  int flat = blockIdx.x;
  int tr = flat >> 5, tc = flat & 31;
  tile_transpose(in, out, 1024, 1024, tr * 32, tc * 32);
}

// ---------------- GEMM core (8-wave, 512 thr, single-buffer, BK=64) ----------------
// C(128x128) = A * Bt^T. Wave grid 4(M)x2(N); wave tile 32x64 -> acc[2][4]
// = 32 AGPRs/wave. XOR-swizzle both sides. Dbuf regressed twice (R11/R13).

DEVFN void gemm_core_ptr8(const bf16* const* aptr, const bf16* __restrict__ Bt,
                          int K, int ldb, int n0, f32x4 acc[2][4]) {
  __shared__ bf16 As[128 * 64];
  __shared__ bf16 Bs[128 * 64];
  const int tid = threadIdx.x;
  const int lane = tid & 63, wave = tid >> 6;        // 0..7
  const int wm = wave >> 1, wn = wave & 1;           // wm 0..3, wn 0..1
  const int lrow = tid >> 3;                         // 0..63
  const int lcolS = ((tid & 7) ^ (lrow & 7)) << 3;

  for (int k0 = 0; k0 < K; k0 += 64) {
    __syncthreads();
#pragma unroll
    for (int i = 0; i < 2; ++i) {
      gll16(aptr[i] + k0, As + (i * 64 + wave * 8) * 64);
      gll16(Bt + (long)(n0 + i * 64 + lrow) * ldb + (k0 + lcolS), Bs + (i * 64 + wave * 8) * 64);
    }
    __syncthreads();
#pragma unroll
    for (int kk = 0; kk < 2; ++kk) {
      const int ac = kk * 32 + (lane >> 4) * 8;
      bf16x8 af[2], bb[4];
#pragma unroll
      for (int x = 0; x < 2; ++x) {
        const int ra = wm * 32 + (lane & 15) + x * 16;
        af[x] = *(const bf16x8*)(As + ra * 64 + (ac ^ ((ra & 7) << 3)));
      }
#pragma unroll
      for (int x = 0; x < 4; ++x) {
        const int rb = wn * 64 + (lane & 15) + x * 16;
        bb[x] = *(const bf16x8*)(Bs + rb * 64 + (ac ^ ((rb & 7) << 3)));
      }
#pragma unroll
      for (int mf = 0; mf < 2; ++mf)
#pragma unroll
        for (int nf = 0; nf < 4; ++nf)
          acc[mf][nf] = __builtin_amdgcn_mfma_f32_16x16x32_bf16(af[mf], bb[nf], acc[mf][nf], 0, 0, 0);
    }
  }
}

// Contiguous-A wrapper for the 8-wave core.
DEVFN void gemm_core_128_8(const bf16* __restrict__ A, const bf16* __restrict__ Bt,
                           int K, int lda, int ldb, int m0, int n0, f32x4 acc[2][4]) {
  const int tid = threadIdx.x;
  const int lrow = tid >> 3;
  const int lcolS = ((tid & 7) ^ (lrow & 7)) << 3;
  const bf16* aptr[2];
#pragma unroll
  for (int i = 0; i < 2; ++i) aptr[i] = A + (long)(m0 + i * 64 + lrow) * lda + lcolS;
  gemm_core_ptr8(aptr, Bt, K, ldb, n0, acc);
}

// ---------------- GEMM core BK=128 (8-wave, 64KB LDS, single-buffer) ----------------
// Halves barriers vs BK=64 (2 per 128 of K instead of 4); 32 MFMA per phase.
// Rows are 256B: 16 chunks of 16B; swizzle chunk ^= (row&15) (both sides).
// Staging round i: wave covers rows i*32+wave*4..+4 (lane>>4 selects row,
// lane&15 the chunk); source col pre-swizzled, LDS dest linear.
// LDS 64KB -> 2 blocks/CU cap ~= measured residency at BK=64, so no TLP loss.

DEVFN void gemm_core_k128(const bf16* __restrict__ A, int lda,
                          const bf16* __restrict__ Bt, int ldb,
                          int K, int n0, f32x4 acc[2][4]) {
  __shared__ bf16 As[128 * 128];
  __shared__ bf16 Bs[128 * 128];
  const int tid = threadIdx.x;
  const int lane = tid & 63, wave = tid >> 6;
  const int wm = wave >> 1, wn = wave & 1;
  const int srow = wave * 4 + (lane >> 4);             // 0..31 per round
  const int schunk = (((lane & 15) ^ (srow & 15)) << 3);

  for (int k0 = 0; k0 < K; k0 += 128) {
    __syncthreads();
#pragma unroll
    for (int i = 0; i < 4; ++i) {
      gll16(A + (long)(i * 32 + srow) * lda + (k0 + schunk), As + (i * 32 + wave * 4) * 128);
      gll16(Bt + (long)(n0 + i * 32 + srow) * ldb + (k0 + schunk), Bs + (i * 32 + wave * 4) * 128);
    }
    __syncthreads();
#pragma unroll
    for (int kk = 0; kk < 4; ++kk) {
      const int ch = kk * 4 + (lane >> 4);             // chunk 0..15
      bf16x8 af[2], bb[4];
#pragma unroll
      for (int x = 0; x < 2; ++x) {
        const int ra = wm * 32 + (lane & 15) + x * 16;
        af[x] = *(const bf16x8*)(As + ra * 128 + ((ch ^ (ra & 15)) << 3));
      }
#pragma unroll
      for (int x = 0; x < 4; ++x) {
        const int rb = wn * 64 + (lane & 15) + x * 16;
        bb[x] = *(const bf16x8*)(Bs + rb * 128 + ((ch ^ (rb & 15)) << 3));
      }
#pragma unroll
      for (int mf = 0; mf < 2; ++mf)
#pragma unroll
        for (int nf = 0; nf < 4; ++nf)
          acc[mf][nf] = __builtin_amdgcn_mfma_f32_16x16x32_bf16(af[mf], bb[nf], acc[mf][nf], 0, 0, 0);
    }
  }
}

// XCD-aware bijective swizzle of the flat block id (grid total % 8 == 0).
DEVFN int xcd_flat() {
  int flat = blockIdx.y * gridDim.x + blockIdx.x;
  int total = gridDim.x * gridDim.y;
  int q = total >> 3;
  return (flat & 7) * q + (flat >> 3);
}

#define EPILOGUE_VARS8                                       \
  const int lane = threadIdx.x & 63, wave = threadIdx.x >> 6; \
  const int wm = wave >> 1, wn = wave & 1;

// ---------------- GEMM kernels (all 8-wave) ----------------

__global__ __launch_bounds__(512, 4) void gemm_qkv_kernel(
    const bf16* __restrict__ X, const bf16* __restrict__ Wt,
    const float* __restrict__ bq, const float* __restrict__ bk, const float* __restrict__ bv,
    bf16* __restrict__ Q, bf16* __restrict__ Kb, bf16* __restrict__ VT) {
  const int m0 = blockIdx.y * 128, n0 = blockIdx.x * 128;
  f32x4 acc[2][4] = {};
  gemm_core_128_8(X, Wt, 1024, 1024, 1024, m0, n0, acc);
  EPILOGUE_VARS8
#pragma unroll
  for (int mf = 0; mf < 2; ++mf)
#pragma unroll
    for (int nf = 0; nf < 4; ++nf)
#pragma unroll
      for (int r = 0; r < 4; ++r) {
        int m = m0 + wm * 32 + mf * 16 + ((lane >> 4) << 2) + r;
        int n = n0 + wn * 64 + nf * 16 + (lane & 15);
        int b = m >> 10, t = m & 1023;
        float v = acc[mf][nf][r];
        if (n < 1024) {
          int h = n >> 6, hd = n & 63;
          Q[((long)(b * 16 + h) * 1024 + t) * 64 + hd] = f2bf(v + bq[n]);
        } else if (n < 2048) {
          int nn = n - 1024, h = nn >> 6, hd = nn & 63;
          Kb[((long)(b * 16 + h) * 1024 + t) * 64 + hd] = f2bf(v + bk[nn]);
        } else {
          int nn = n - 2048, h = nn >> 6, hd = nn & 63;
          VT[((long)(b * 16 + h) * 64 + hd) * 1024 + t] = f2bf(v + bv[nn]);
        }
      }
}

__global__ __launch_bounds__(512, 4) void gemm_wo_kernel(
    const bf16* __restrict__ AO, const bf16* __restrict__ Wot,
    const float* __restrict__ bo, const float* __restrict__ src,
    float* __restrict__ xres) {
  const int m0 = blockIdx.y * 128, n0 = blockIdx.x * 128;
  f32x4 acc[2][4] = {};
  gemm_core_128_8(AO, Wot, 1024, 1024, 1024, m0, n0, acc);
  EPILOGUE_VARS8
#pragma unroll
  for (int mf = 0; mf < 2; ++mf)
#pragma unroll
    for (int nf = 0; nf < 4; ++nf)
#pragma unroll
      for (int r = 0; r < 4; ++r) {
        int m = m0 + wm * 32 + mf * 16 + ((lane >> 4) << 2) + r;
        int n = n0 + wn * 64 + nf * 16 + (lane & 15);
        long idx = (long)m * 1024 + n;
        xres[idx] = acc[mf][nf][r] + bo[n] + src[idx];
      }
}

// ---------------- MoE: tile table + combined-expert FFN (8-wave) ----------------
// tbl[gt] = (e<<8) | local_tile_idx.  H rows for tile gt live at gt*128.

__global__ void tiles_kernel(const int* __restrict__ cnt, int* __restrict__ tbl,
                             int* __restrict__ tot) {
  if (threadIdx.x != 0 || blockIdx.x != 0) return;
  int acc = 0;
  for (int e = 0; e < 4; ++e) {
    int t = (cnt[e] + 127) >> 7;
    for (int i = 0; i < t; ++i) tbl[acc + i] = (e << 8) | i;
    acc += t;
  }
  *tot = acc;
}

// ffn1 block-order: 2-D grouped mapping (R18: dropped ffn1 out of top-5).
__global__ __launch_bounds__(512, 4) void ffn1_all_kernel(
    const bf16* __restrict__ X, const bf16* __restrict__ EW1T, const float* __restrict__ eb1,
    const int* __restrict__ list, const int* __restrict__ cnt,
    const int* __restrict__ tbl, const int* __restrict__ tot,
    bf16* __restrict__ H) {
  int swz = xcd_flat();                 // grid 32 x 72 = 2304
  int gtg = swz >> 8;                   // 0..8
  int rem = swz & 255;
  int nb = rem >> 3, gti = rem & 7;
  int gt = gtg * 8 + gti;
  if (gt >= *tot) return;
  const int ent = tbl[gt];
  const int e = ent >> 8, lti = ent & 255;
  const int nc = cnt[e];
  const int tid = threadIdx.x;
  const int lrow = tid >> 3;                        // 0..63
  const int lcolS = ((tid & 7) ^ (lrow & 7)) << 3;
  const bf16* aptr[2];
#pragma unroll
  for (int i = 0; i < 2; ++i) {
    int lm = lti * 128 + i * 64 + lrow;
    int pk = list[e * 4096 + (lm < nc ? lm : nc - 1)];
    aptr[i] = X + (long)(pk & 0xFFF) * 1024 + lcolS;
  }
  f32x4 acc[2][4] = {};
  gemm_core_ptr8(aptr, EW1T + (long)e * 4096 * 1024, 1024, 1024, nb * 128, acc);
  EPILOGUE_VARS8
  const int hbase = gt * 128;
#pragma unroll
  for (int mf = 0; mf < 2; ++mf)
#pragma unroll
    for (int nf = 0; nf < 4; ++nf)
#pragma unroll
      for (int r = 0; r < 4; ++r) {
        int ml = wm * 32 + mf * 16 + ((lane >> 4) << 2) + r;
        int n = nb * 128 + wn * 64 + nf * 16 + (lane & 15);
        float v = acc[mf][nf][r] + eb1[e * 4096 + n];
        H[(long)(hbase + ml) * 4096 + n] = f2bf(v > 0.f ? v : 0.f);
      }
}

// FFN2 split-K=2, BK=128 core (half the barriers of BK=64).
__global__ __launch_bounds__(512, 4) void ffn2_all_kernel(
    const bf16* __restrict__ H, const bf16* __restrict__ EW2T,
    const float* __restrict__ eb2, const float* __restrict__ comb,
    const int* __restrict__ list, const int* __restrict__ cnt,
    const int* __restrict__ tbl, const int* __restrict__ tot,
    bf16* __restrict__ ff4) {
  int swz = xcd_flat();
  int gt = swz >> 4;
  int xk = swz & 15;
  int nb = xk & 7, ks = xk >> 3;
  if (gt >= *tot) return;
  const int ent = tbl[gt];
  const int e = ent >> 8, lti = ent & 255;
  const int nc = cnt[e];
  f32x4 acc[2][4] = {};
  gemm_core_k128(H + (long)gt * 128 * 4096 + ks * 2048, 4096,
                 EW2T + (long)e * 1024 * 4096 + ks * 2048, 4096,
                 2048, nb * 128, acc);
  EPILOGUE_VARS8
#pragma unroll
  for (int mf = 0; mf < 2; ++mf)
#pragma unroll
    for (int nf = 0; nf < 4; ++nf)
#pragma unroll
      for (int r = 0; r < 4; ++r) {
        int ml = wm * 32 + mf * 16 + ((lane >> 4) << 2) + r;
        int lm = lti * 128 + ml;
        if (lm < nc) {
          int pk = list[e * 4096 + lm];
          int t = pk & 0xFFF, slot = (pk >> 12) & 1;
          int n = nb * 128 + wn * 64 + nf * 16 + (lane & 15);
          float c = comb[(long)t * 4 + e];
          float v = acc[mf][nf][r] + (ks == 0 ? eb2[e * 1024 + n] : 0.f);
          ff4[((long)t * 4 + slot * 2 + ks) * 1024 + n] = f2bf(c * v);
        }
      }
}

// ---------------- attention (8-wave, Q-tile 128) ----------------

__global__ __launch_bounds__(512, 4) void attn_kernel(
    const bf16* __restrict__ Q, const bf16* __restrict__ Kg, const bf16* __restrict__ VT,
    const float* __restrict__ frac, const float* __restrict__ attn_bias,
    bf16* __restrict__ O) {
  const int qt = blockIdx.x, h = blockIdx.y, b = blockIdx.z;
  const int tid = threadIdx.x, lane = tid & 63, wave = tid >> 6;  // wave 0..7
  const int q0 = qt * 128;

  __shared__ bf16 Qs[128 * 64];   // 16 KB
  __shared__ bf16 Ks[64 * 64];    // 8 KB
  __shared__ bf16 VTs[64 * 64];   // 8 KB
  __shared__ bf16 Ps[8][16 * 64]; // 16 KB

  float sb = attn_bias[lane];
#pragma unroll
  for (int off = 32; off >= 1; off >>= 1) sb += __shfl_xor(sb, off);

  const long bh = (long)(b * 16 + h);
  const bf16* Qg = Q + (bh * 1024 + q0) * 64;
  const bf16* Kgh = Kg + bh * 1024 * 64;
  const bf16* VTgh = VT + bh * 64 * 1024;
  const float* fr = frac + b * 1024;

  const int lrow = tid >> 3;                          // 0..63
  const int lcolS = (((tid & 7) ^ (lrow & 7)) * 8);
#pragma unroll
  for (int i = 0; i < 2; ++i)
    gll16(Qg + (long)(i * 64 + lrow) * 64 + lcolS, Qs + (i * 64 + wave * 8) * 64);

  float fi[4];
  {
    int rbase = q0 + wave * 16 + ((lane >> 4) << 2);
#pragma unroll
    for (int r = 0; r < 4; ++r) fi[r] = fr[rbase + r];
  }

  float mrow[4] = {-1e30f, -1e30f, -1e30f, -1e30f};
  float lrw[4] = {0.f, 0.f, 0.f, 0.f};
  f32x4 acco[4] = {};
  const float scale = 0.125f;

  for (int kv0 = 0; kv0 < 1024; kv0 += 64) {
    __syncthreads();
    gll16(Kgh + (long)(kv0 + lrow) * 64 + lcolS, Ks + (wave * 8) * 64);
    gll16(VTgh + (long)lrow * 1024 + kv0 + lcolS, VTs + (wave * 8) * 64);
    __syncthreads();

    f32x4 sacc[4] = {};
#pragma unroll
    for (int kk = 0; kk < 2; ++kk) {
      const int ac = kk * 32 + (lane >> 4) * 8;
      const int rq = wave * 16 + (lane & 15);
      bf16x8 aq = *(const bf16x8*)(Qs + rq * 64 + (ac ^ ((rq & 7) << 3)));
#pragma unroll
      for (int nf = 0; nf < 4; ++nf) {
        const int rk = nf * 16 + (lane & 15);
        bf16x8 bk_ = *(const bf16x8*)(Ks + rk * 64 + (ac ^ ((rk & 7) << 3)));
        sacc[nf] = __builtin_amdgcn_mfma_f32_16x16x32_bf16(aq, bk_, sacc[nf], 0, 0, 0);
      }
    }

    float fj[4];
#pragma unroll
    for (int nf = 0; nf < 4; ++nf) fj[nf] = fr[kv0 + nf * 16 + (lane & 15)];

    float sv[4][4];
#pragma unroll
    for (int nf = 0; nf < 4; ++nf)
#pragma unroll
      for (int r = 0; r < 4; ++r) {
        float fac = (fj[nf] - fi[r]) * __builtin_amdgcn_rcpf(fi[r] * fj[nf] + 1e-8f);
        sv[nf][r] = (sacc[nf][r] + fac * sb) * scale;
      }

#pragma unroll
    for (int r = 0; r < 4; ++r) {
      float mx = fmaxf(fmaxf(sv[0][r], sv[1][r]), fmaxf(sv[2][r], sv[3][r]));
#pragma unroll
      for (int mk = 8; mk >= 1; mk >>= 1) mx = fmaxf(mx, __shfl_xor(mx, mk));
      float mnew = fmaxf(mrow[r], mx);
      float corr = __expf(mrow[r] - mnew);
      float rs = 0.f;
      const int pr = ((lane >> 4) << 2) + r;
#pragma unroll
      for (int nf = 0; nf < 4; ++nf) {
        float p = __expf(sv[nf][r] - mnew);
        rs += p;
        int pc = nf * 16 + (lane & 15);
        Ps[wave][pr * 64 + (pc ^ ((pr & 7) << 3))] = f2bf(p);
      }
#pragma unroll
      for (int mk = 8; mk >= 1; mk >>= 1) rs += __shfl_xor(rs, mk);
      lrw[r] = lrw[r] * corr + rs;
      mrow[r] = mnew;
#pragma unroll
      for (int nf = 0; nf < 4; ++nf) acco[nf][r] *= corr;
    }

#pragma unroll
    for (int kk = 0; kk < 2; ++kk) {
      const int ac = kk * 32 + (lane >> 4) * 8;
      const int rp = lane & 15;
      bf16x8 ap = *(const bf16x8*)(Ps[wave] + rp * 64 + (ac ^ ((rp & 7) << 3)));
#pragma unroll
      for (int nf = 0; nf < 4; ++nf) {
        const int rv = nf * 16 + (lane & 15);
        bf16x8 bv_ = *(const bf16x8*)(VTs + rv * 64 + (ac ^ ((rv & 7) << 3)));
        acco[nf] = __builtin_amdgcn_mfma_f32_16x16x32_bf16(ap, bv_, acco[nf], 0, 0, 0);
      }
    }
  }

#pragma unroll
  for (int nf = 0; nf < 4; ++nf)
#pragma unroll
    for (int r = 0; r < 4; ++r) {
      int t = q0 + wave * 16 + ((lane >> 4) << 2) + r;
      int d = h * 64 + nf * 16 + (lane & 15);
      O[((long)b * 1024 + t) * 1024 + d] = f2bf(acco[nf][r] / lrw[r]);
    }
}

// ---------------- fused LN1 + gate ----------------

__global__ __launch_bounds__(256) void ln1_gate_kernel(
    const float* __restrict__ xres,
    const float* __restrict__ g, const float* __restrict__ beta,
    const float* __restrict__ gw, const float* __restrict__ gb,
    float* __restrict__ xf, bf16* __restrict__ xb, float* __restrict__ comb) {
  const int row = blockIdx.x, tid = threadIdx.x;
  const long base = (long)row * 1024;
  float4 v4 = ((const float4*)(xres + base))[tid];
  float a[4] = {v4.x, v4.y, v4.z, v4.w};
  float s = a[0] + a[1] + a[2] + a[3];
  float s2 = a[0] * a[0] + a[1] * a[1] + a[2] * a[2] + a[3] * a[3];
#pragma unroll
  for (int off = 32; off >= 1; off >>= 1) { s += __shfl_xor(s, off); s2 += __shfl_xor(s2, off); }
  __shared__ float red[8];
  __shared__ float redg[4][4];
  const int wave = tid >> 6, lane = tid & 63;
  if (lane == 0) { red[wave] = s; red[4 + wave] = s2; }
  __syncthreads();
  s = red[0] + red[1] + red[2] + red[3];
  s2 = red[4] + red[5] + red[6] + red[7];
  float mu = s * (1.f / 1024.f);
  float var = s2 * (1.f / 1024.f) - mu * mu;
  float rstd = rsqrtf(var + 1e-5f);
  int c = tid * 4;
  float p[4] = {0.f, 0.f, 0.f, 0.f};
#pragma unroll
  for (int j = 0; j < 4; ++j) {
    float xv = (a[j] - mu) * rstd * g[c + j] + beta[c + j];
    xf[base + c + j] = xv;
    xb[base + c + j] = f2bf(xv);
#pragma unroll
    for (int e = 0; e < 4; ++e) p[e] += xv * gw[(c + j) * 4 + e];
  }
#pragma unroll
  for (int off = 32; off >= 1; off >>= 1)
#pragma unroll
    for (int e = 0; e < 4; ++e) p[e] += __shfl_xor(p[e], off);
  if (lane == 0)
#pragma unroll
    for (int e = 0; e < 4; ++e) redg[wave][e] = p[e];
  __syncthreads();
  if (tid == 0) {
    float sc[4];
    for (int e = 0; e < 4; ++e)
      sc[e] = redg[0][e] + redg[1][e] + redg[2][e] + redg[3][e] + gb[e];
    float mx = fmaxf(fmaxf(sc[0], sc[1]), fmaxf(sc[2], sc[3]));
    float se[4], ssum = 0.f;
    for (int e = 0; e < 4; ++e) { se[e] = __expf(sc[e] - mx); ssum += se[e]; }
    for (int e = 0; e < 4; ++e) se[e] /= ssum;
    int i1 = 0;
    for (int e = 1; e < 4; ++e) if (se[e] > se[i1]) i1 = e;
    int i2 = -1;
    for (int e = 0; e < 4; ++e) { if (e == i1) continue; if (i2 < 0 || se[e] > se[i2]) i2 = e; }
    for (int e = 0; e < 4; ++e) comb[(long)row * 4 + e] = (e == i1 || e == i2) ? se[e] : 0.f;
  }
}

// LN2: out = LN(xf + sum_{j<4} ff4[row][j])
__global__ __launch_bounds__(256) void ln2_kernel(
    const float* __restrict__ xf, const bf16* __restrict__ ff4,
    const float* __restrict__ g, const float* __restrict__ beta,
    float* __restrict__ out) {
  const int row = blockIdx.x, tid = threadIdx.x;
  const long base = (long)row * 1024;
  float4 v4 = ((const float4*)(xf + base))[tid];
  const bf16* frw = ff4 + (long)row * 4096;
  float a[4] = {v4.x, v4.y, v4.z, v4.w};
#pragma unroll
  for (int j = 0; j < 4; ++j) {
    ushort4 f = ((const ushort4*)(frw + j * 1024))[tid];
    a[0] += b2f(f.x); a[1] += b2f(f.y); a[2] += b2f(f.z); a[3] += b2f(f.w);
  }
  float s = a[0] + a[1] + a[2] + a[3];
  float s2 = a[0] * a[0] + a[1] * a[1] + a[2] * a[2] + a[3] * a[3];
#pragma unroll
  for (int off = 32; off >= 1; off >>= 1) { s += __shfl_xor(s, off); s2 += __shfl_xor(s2, off); }
  __shared__ float red[8];
  const int wave = tid >> 6, lane = tid & 63;
  if (lane == 0) { red[wave] = s; red[4 + wave] = s2; }
  __syncthreads();
  s = red[0] + red[1] + red[2] + red[3];
  s2 = red[4] + red[5] + red[6] + red[7];
  float mu = s * (1.f / 1024.f);
  float var = s2 * (1.f / 1024.f) - mu * mu;
  float rstd = rsqrtf(var + 1e-5f);
  int c = tid * 4;
#pragma unroll
  for (int j = 0; j < 4; ++j)
    out[base + c + j] = (a[j] - mu) * rstd * g[c + j] + beta[c + j];
}

// ---------------- MoE token compaction ----------------

__global__ __launch_bounds__(256) void compact_kernel(
    const float* __restrict__ comb, int* __restrict__ cnt, int* __restrict__ list) {
  int t = blockIdx.x * 256 + threadIdx.x;
  int slot = 0;
#pragma unroll
  for (int e = 0; e < 4; ++e) {
    float c = comb[(long)t * 4 + e];
    if (c != 0.f) {
      int pos = atomicAdd(&cnt[e], 1);
      list[e * 4096 + pos] = t | (slot << 12);
      slot++;
    }
  }
}

// ---------------- launch ----------------

extern "C" void kernel_launch(void* const* d_in, const int* in_sizes, int n_in,
                              void* d_out, int out_size, void* d_ws, size_t ws_size,
                              hipStream_t stream) {
  (void)in_sizes; (void)n_in; (void)out_size; (void)ws_size;
  const float* src = (const float*)d_in[0];
  const float* frac = (const float*)d_in[1];
  const float* Wq = (const float*)d_in[2];
  const float* bq = (const float*)d_in[3];
  const float* Wk = (const float*)d_in[4];
  const float* bk = (const float*)d_in[5];
  const float* Wv = (const float*)d_in[6];
  const float* bv = (const float*)d_in[7];
  const float* attn_bias = (const float*)d_in[8];
  const float* Wo = (const float*)d_in[9];
  const float* bo = (const float*)d_in[10];
  const float* gate_w = (const float*)d_in[11];
  const float* gate_b = (const float*)d_in[12];
  const float* ew1 = (const float*)d_in[13];
  const float* eb1 = (const float*)d_in[14];
  const float* ew2 = (const float*)d_in[15];
  const float* eb2 = (const float*)d_in[16];
  const float* ln1_g = (const float*)d_in[17];
  const float* ln1_b = (const float*)d_in[18];
  const float* ln2_g = (const float*)d_in[19];
  const float* ln2_b = (const float*)d_in[20];
  float* out = (float*)d_out;

  char* ws = (char*)d_ws;
  bf16* XB    = (bf16*)(ws + 0);                    // 8 MB: src bf16, later x bf16
  bf16* WQKVT = (bf16*)(ws + ((size_t)8 << 20));    // 6 MB
  bf16* WOT   = (bf16*)(ws + ((size_t)14 << 20));   // 2 MB
  bf16* EW1T  = (bf16*)(ws + ((size_t)16 << 20));   // 32 MB
  bf16* EW2T  = (bf16*)(ws + ((size_t)48 << 20));   // 32 MB
  bf16* QB    = (bf16*)(ws + ((size_t)80 << 20));   // 8 MB  (QB..AOB reused as FF4 after wo)
  bf16* KB    = (bf16*)(ws + ((size_t)88 << 20));   // 8 MB
  bf16* VTB   = (bf16*)(ws + ((size_t)96 << 20));   // 8 MB
  bf16* AOB   = (bf16*)(ws + ((size_t)104 << 20));  // 8 MB
  bf16* FF4   = QB;                                 // [4096][4][1024] bf16 = 32 MB
  float* XRES = (float*)(ws + ((size_t)112 << 20)); // 16 MB
  float* XF   = (float*)(ws + ((size_t)128 << 20)); // 16 MB
  float* COMB = (float*)(ws + ((size_t)144 << 20)); // 64 KB
  int*   LIST = (int*)(ws + ((size_t)144 << 20) + (64 << 10)); // 64 KB
  int*   CNT  = (int*)(ws + ((size_t)144 << 20) + (128 << 10)); // 16 B
  int*   TOT  = CNT + 8;
  int*   TILE = CNT + 16;                           // 128 ints
  bf16*  HALL = (bf16*)(ws + ((size_t)146 << 20));  // 8704 rows x 4096 = ~71.3 MB

  dim3 tb(32, 8);
  cast_bf16_kernel<<<4096, 256, 0, stream>>>(src, XB, (4 * 1024 * 1024) / 4);
  w_qkvo_kernel<<<dim3(1024, 4), tb, 0, stream>>>(Wq, Wk, Wv, Wo, WQKVT, WOT);
  w_experts_kernel<<<dim3(4096, 8), tb, 0, stream>>>(ew1, ew2, EW1T, EW2T);

  gemm_qkv_kernel<<<dim3(24, 32), 512, 0, stream>>>(XB, WQKVT, bq, bk, bv, QB, KB, VTB);
  attn_kernel<<<dim3(8, 16, 4), 512, 0, stream>>>(QB, KB, VTB, frac, attn_bias, AOB);
  gemm_wo_kernel<<<dim3(8, 32), 512, 0, stream>>>(AOB, WOT, bo, src, XRES);
  ln1_gate_kernel<<<4096, 256, 0, stream>>>(XRES, ln1_g, ln1_b, gate_w, gate_b, XF, XB, COMB);
  (void)hipMemsetAsync(CNT, 0, 4 * sizeof(int), stream);
  compact_kernel<<<16, 256, 0, stream>>>(COMB, CNT, LIST);

  tiles_kernel<<<1, 64, 0, stream>>>(CNT, TILE, TOT);
  ffn1_all_kernel<<<dim3(32, 72), 512, 0, stream>>>(XB, EW1T, eb1, LIST, CNT, TILE, TOT, HALL);
  ffn2_all_kernel<<<dim3(16, 68), 512, 0, stream>>>(HALL, EW2T, eb2, COMB, LIST, CNT, TILE, TOT, FF4);
  ln2_kernel<<<4096, 256, 0, stream>>>(XF, FF4, ln2_g, ln2_b, out);
}

// Round 20
// 426.722 us; speedup vs baseline: 1.0310x; 1.0310x over previous
//
#include <hip/hip_runtime.h>
#include <hip/hip_bf16.h>
#include <stdint.h>

typedef __hip_bfloat16 bf16;
typedef __attribute__((ext_vector_type(8))) short bf16x8;
typedef __attribute__((ext_vector_type(4))) float f32x4;

#define DEVFN static __device__ __forceinline__

DEVFN void gll16(const bf16* g, bf16* l) {
  __builtin_amdgcn_global_load_lds((const __attribute__((address_space(1))) void*)g,
                                   (__attribute__((address_space(3))) void*)l, 16, 0, 0);
}

DEVFN bf16 f2bf(float f) { return __float2bfloat16(f); }
DEVFN float b2f(unsigned short u) { return __bfloat162float(__builtin_bit_cast(bf16, u)); }

// ---------------- cast / transpose ----------------

__global__ __launch_bounds__(256) void cast_bf16_kernel(const float* __restrict__ in,
                                                        bf16* __restrict__ out, int n4) {
  int i = blockIdx.x * 256 + threadIdx.x;
  if (i >= n4) return;
  float4 v = ((const float4*)in)[i];
  ushort4 o;
  o.x = __builtin_bit_cast(unsigned short, f2bf(v.x));
  o.y = __builtin_bit_cast(unsigned short, f2bf(v.y));
  o.z = __builtin_bit_cast(unsigned short, f2bf(v.z));
  o.w = __builtin_bit_cast(unsigned short, f2bf(v.w));
  ((ushort4*)out)[i] = o;
}

DEVFN void tile_transpose(const float* __restrict__ in, bf16* __restrict__ out,
                          int R, int C, int r0, int c0) {
  __shared__ bf16 tile[32][33];
  for (int i = threadIdx.y; i < 32; i += 8)
    tile[i][threadIdx.x] = f2bf(in[(long)(r0 + i) * C + (c0 + threadIdx.x)]);
  __syncthreads();
  for (int i = threadIdx.y; i < 32; i += 8)
    out[(long)(c0 + i) * R + (r0 + threadIdx.x)] = tile[threadIdx.x][i];
}

// All 8 expert weight mats in one launch: z = e*2 + {0:ew1, 1:ew2}; 4096 tiles each.
__global__ __launch_bounds__(256) void w_experts_kernel(
    const float* __restrict__ ew1, const float* __restrict__ ew2,
    bf16* __restrict__ EW1T, bf16* __restrict__ EW2T) {
  const int z = blockIdx.y, e = z >> 1;
  const float* in;
  bf16* out;
  int R, C, TC;
  if ((z & 1) == 0) { in = ew1 + (long)e * 1024 * 4096; out = EW1T + (long)e * 4096 * 1024; R = 1024; C = 4096; TC = 128; }
  else              { in = ew2 + (long)e * 4096 * 1024; out = EW2T + (long)e * 1024 * 4096; R = 4096; C = 1024; TC = 32; }
  int flat = blockIdx.x;
  int tr = flat / TC, tc = flat - tr * TC;
  tile_transpose(in, out, R, C, tr * 32, tc * 32);
}

// Wq/Wk/Wv/Wo (all 1024x1024) in one launch: z picks matrix; 1024 tiles each.
__global__ __launch_bounds__(256) void w_qkvo_kernel(
    const float* __restrict__ Wq, const float* __restrict__ Wk,
    const float* __restrict__ Wv, const float* __restrict__ Wo,
    bf16* __restrict__ WQKVT, bf16* __restrict__ WOT) {
  const int z = blockIdx.y;
  const float* in = z == 0 ? Wq : z == 1 ? Wk : z == 2 ? Wv : Wo;
  bf16* out = z == 3 ? WOT : WQKVT + (long)z * 1024 * 1024;
  int flat = blockIdx.x;
  int tr = flat >> 5, tc = flat & 31;
  tile_transpose(in, out, 1024, 1024, tr * 32, tc * 32);
}

// ---------------- GEMM core (8-wave, 512 thr, single-buffer, BK=64) ----------------
// C(128x128) = A * Bt^T. Wave grid 4(M)x2(N); wave tile 32x64 -> acc[2][4]
// = 32 AGPRs/wave. XOR-swizzle both sides. STRUCTURAL NOTES: dbuf regressed
// twice (R11 4-wave, R13 8-wave) and BK=128 regressed (R19) — every variant
// that needs 64KB LDS drops residency below the TLP break-even. This BK=64
// 32KB single-buffer core (~26% MfmaUtil, ~42% occupancy) is the plateau of
// the 2-barrier structure.

DEVFN void gemm_core_ptr8(const bf16* const* aptr, const bf16* __restrict__ Bt,
                          int K, int ldb, int n0, f32x4 acc[2][4]) {
  __shared__ bf16 As[128 * 64];
  __shared__ bf16 Bs[128 * 64];
  const int tid = threadIdx.x;
  const int lane = tid & 63, wave = tid >> 6;        // 0..7
  const int wm = wave >> 1, wn = wave & 1;           // wm 0..3, wn 0..1
  const int lrow = tid >> 3;                         // 0..63
  const int lcolS = ((tid & 7) ^ (lrow & 7)) << 3;

  for (int k0 = 0; k0 < K; k0 += 64) {
    __syncthreads();
#pragma unroll
    for (int i = 0; i < 2; ++i) {
      gll16(aptr[i] + k0, As + (i * 64 + wave * 8) * 64);
      gll16(Bt + (long)(n0 + i * 64 + lrow) * ldb + (k0 + lcolS), Bs + (i * 64 + wave * 8) * 64);
    }
    __syncthreads();
#pragma unroll
    for (int kk = 0; kk < 2; ++kk) {
      const int ac = kk * 32 + (lane >> 4) * 8;
      bf16x8 af[2], bb[4];
#pragma unroll
      for (int x = 0; x < 2; ++x) {
        const int ra = wm * 32 + (lane & 15) + x * 16;
        af[x] = *(const bf16x8*)(As + ra * 64 + (ac ^ ((ra & 7) << 3)));
      }
#pragma unroll
      for (int x = 0; x < 4; ++x) {
        const int rb = wn * 64 + (lane & 15) + x * 16;
        bb[x] = *(const bf16x8*)(Bs + rb * 64 + (ac ^ ((rb & 7) << 3)));
      }
#pragma unroll
      for (int mf = 0; mf < 2; ++mf)
#pragma unroll
        for (int nf = 0; nf < 4; ++nf)
          acc[mf][nf] = __builtin_amdgcn_mfma_f32_16x16x32_bf16(af[mf], bb[nf], acc[mf][nf], 0, 0, 0);
    }
  }
}

// Contiguous-A wrapper for the 8-wave core.
DEVFN void gemm_core_128_8(const bf16* __restrict__ A, const bf16* __restrict__ Bt,
                           int K, int lda, int ldb, int m0, int n0, f32x4 acc[2][4]) {
  const int tid = threadIdx.x;
  const int lrow = tid >> 3;
  const int lcolS = ((tid & 7) ^ (lrow & 7)) << 3;
  const bf16* aptr[2];
#pragma unroll
  for (int i = 0; i < 2; ++i) aptr[i] = A + (long)(m0 + i * 64 + lrow) * lda + lcolS;
  gemm_core_ptr8(aptr, Bt, K, ldb, n0, acc);
}

// XCD-aware bijective swizzle of the flat block id (grid total % 8 == 0).
DEVFN int xcd_flat() {
  int flat = blockIdx.y * gridDim.x + blockIdx.x;
  int total = gridDim.x * gridDim.y;
  int q = total >> 3;
  return (flat & 7) * q + (flat >> 3);
}

#define EPILOGUE_VARS8                                       \
  const int lane = threadIdx.x & 63, wave = threadIdx.x >> 6; \
  const int wm = wave >> 1, wn = wave & 1;

// ---------------- GEMM kernels (all 8-wave) ----------------

__global__ __launch_bounds__(512, 4) void gemm_qkv_kernel(
    const bf16* __restrict__ X, const bf16* __restrict__ Wt,
    const float* __restrict__ bq, const float* __restrict__ bk, const float* __restrict__ bv,
    bf16* __restrict__ Q, bf16* __restrict__ Kb, bf16* __restrict__ VT) {
  const int m0 = blockIdx.y * 128, n0 = blockIdx.x * 128;
  f32x4 acc[2][4] = {};
  gemm_core_128_8(X, Wt, 1024, 1024, 1024, m0, n0, acc);
  EPILOGUE_VARS8
#pragma unroll
  for (int mf = 0; mf < 2; ++mf)
#pragma unroll
    for (int nf = 0; nf < 4; ++nf)
#pragma unroll
      for (int r = 0; r < 4; ++r) {
        int m = m0 + wm * 32 + mf * 16 + ((lane >> 4) << 2) + r;
        int n = n0 + wn * 64 + nf * 16 + (lane & 15);
        int b = m >> 10, t = m & 1023;
        float v = acc[mf][nf][r];
        if (n < 1024) {
          int h = n >> 6, hd = n & 63;
          Q[((long)(b * 16 + h) * 1024 + t) * 64 + hd] = f2bf(v + bq[n]);
        } else if (n < 2048) {
          int nn = n - 1024, h = nn >> 6, hd = nn & 63;
          Kb[((long)(b * 16 + h) * 1024 + t) * 64 + hd] = f2bf(v + bk[nn]);
        } else {
          int nn = n - 2048, h = nn >> 6, hd = nn & 63;
          VT[((long)(b * 16 + h) * 64 + hd) * 1024 + t] = f2bf(v + bv[nn]);
        }
      }
}

__global__ __launch_bounds__(512, 4) void gemm_wo_kernel(
    const bf16* __restrict__ AO, const bf16* __restrict__ Wot,
    const float* __restrict__ bo, const float* __restrict__ src,
    float* __restrict__ xres) {
  const int m0 = blockIdx.y * 128, n0 = blockIdx.x * 128;
  f32x4 acc[2][4] = {};
  gemm_core_128_8(AO, Wot, 1024, 1024, 1024, m0, n0, acc);
  EPILOGUE_VARS8
#pragma unroll
  for (int mf = 0; mf < 2; ++mf)
#pragma unroll
    for (int nf = 0; nf < 4; ++nf)
#pragma unroll
      for (int r = 0; r < 4; ++r) {
        int m = m0 + wm * 32 + mf * 16 + ((lane >> 4) << 2) + r;
        int n = n0 + wn * 64 + nf * 16 + (lane & 15);
        long idx = (long)m * 1024 + n;
        xres[idx] = acc[mf][nf][r] + bo[n] + src[idx];
      }
}

// ---------------- MoE: tile table + combined-expert FFN (8-wave) ----------------
// tbl[gt] = (e<<8) | local_tile_idx.  H rows for tile gt live at gt*128.

__global__ void tiles_kernel(const int* __restrict__ cnt, int* __restrict__ tbl,
                             int* __restrict__ tot) {
  if (threadIdx.x != 0 || blockIdx.x != 0) return;
  int acc = 0;
  for (int e = 0; e < 4; ++e) {
    int t = (cnt[e] + 127) >> 7;
    for (int i = 0; i < t; ++i) tbl[acc + i] = (e << 8) | i;
    acc += t;
  }
  *tot = acc;
}

// ffn1 block-order: 2-D grouped mapping (R18: dropped ffn1 out of top-5).
__global__ __launch_bounds__(512, 4) void ffn1_all_kernel(
    const bf16* __restrict__ X, const bf16* __restrict__ EW1T, const float* __restrict__ eb1,
    const int* __restrict__ list, const int* __restrict__ cnt,
    const int* __restrict__ tbl, const int* __restrict__ tot,
    bf16* __restrict__ H) {
  int swz = xcd_flat();                 // grid 32 x 72 = 2304
  int gtg = swz >> 8;                   // 0..8
  int rem = swz & 255;
  int nb = rem >> 3, gti = rem & 7;
  int gt = gtg * 8 + gti;
  if (gt >= *tot) return;
  const int ent = tbl[gt];
  const int e = ent >> 8, lti = ent & 255;
  const int nc = cnt[e];
  const int tid = threadIdx.x;
  const int lrow = tid >> 3;                        // 0..63
  const int lcolS = ((tid & 7) ^ (lrow & 7)) << 3;
  const bf16* aptr[2];
#pragma unroll
  for (int i = 0; i < 2; ++i) {
    int lm = lti * 128 + i * 64 + lrow;
    int pk = list[e * 4096 + (lm < nc ? lm : nc - 1)];
    aptr[i] = X + (long)(pk & 0xFFF) * 1024 + lcolS;
  }
  f32x4 acc[2][4] = {};
  gemm_core_ptr8(aptr, EW1T + (long)e * 4096 * 1024, 1024, 1024, nb * 128, acc);
  EPILOGUE_VARS8
  const int hbase = gt * 128;
#pragma unroll
  for (int mf = 0; mf < 2; ++mf)
#pragma unroll
    for (int nf = 0; nf < 4; ++nf)
#pragma unroll
      for (int r = 0; r < 4; ++r) {
        int ml = wm * 32 + mf * 16 + ((lane >> 4) << 2) + r;
        int n = nb * 128 + wn * 64 + nf * 16 + (lane & 15);
        float v = acc[mf][nf][r] + eb1[e * 4096 + n];
        H[(long)(hbase + ml) * 4096 + n] = f2bf(v > 0.f ? v : 0.f);
      }
}

// FFN2 split-K=2: x dim encodes (ks, nb); partials -> ff4[token][slot*2+ks][1024].
// BK=64 core (BK=128 regressed in R19: 64KB LDS -> occupancy 41->30%).
__global__ __launch_bounds__(512, 4) void ffn2_all_kernel(
    const bf16* __restrict__ H, const bf16* __restrict__ EW2T,
    const float* __restrict__ eb2, const float* __restrict__ comb,
    const int* __restrict__ list, const int* __restrict__ cnt,
    const int* __restrict__ tbl, const int* __restrict__ tot,
    bf16* __restrict__ ff4) {
  int swz = xcd_flat();
  int gt = swz >> 4;
  int xk = swz & 15;
  int nb = xk & 7, ks = xk >> 3;
  if (gt >= *tot) return;
  const int ent = tbl[gt];
  const int e = ent >> 8, lti = ent & 255;
  const int nc = cnt[e];
  const int tid = threadIdx.x;
  const int lrow = tid >> 3;
  const int lcolS = ((tid & 7) ^ (lrow & 7)) << 3;
  const bf16* Abase = H + (long)gt * 128 * 4096 + ks * 2048;
  const bf16* aptr[2];
#pragma unroll
  for (int i = 0; i < 2; ++i) aptr[i] = Abase + (long)(i * 64 + lrow) * 4096 + lcolS;
  f32x4 acc[2][4] = {};
  gemm_core_ptr8(aptr, EW2T + (long)e * 1024 * 4096 + ks * 2048, 2048, 4096, nb * 128, acc);
  EPILOGUE_VARS8
#pragma unroll
  for (int mf = 0; mf < 2; ++mf)
#pragma unroll
    for (int nf = 0; nf < 4; ++nf)
#pragma unroll
      for (int r = 0; r < 4; ++r) {
        int ml = wm * 32 + mf * 16 + ((lane >> 4) << 2) + r;
        int lm = lti * 128 + ml;
        if (lm < nc) {
          int pk = list[e * 4096 + lm];
          int t = pk & 0xFFF, slot = (pk >> 12) & 1;
          int n = nb * 128 + wn * 64 + nf * 16 + (lane & 15);
          float c = comb[(long)t * 4 + e];
          float v = acc[mf][nf][r] + (ks == 0 ? eb2[e * 1024 + n] : 0.f);
          ff4[((long)t * 4 + slot * 2 + ks) * 1024 + n] = f2bf(c * v);
        }
      }
}

// ---------------- attention (8-wave, Q-tile 128) ----------------

__global__ __launch_bounds__(512, 4) void attn_kernel(
    const bf16* __restrict__ Q, const bf16* __restrict__ Kg, const bf16* __restrict__ VT,
    const float* __restrict__ frac, const float* __restrict__ attn_bias,
    bf16* __restrict__ O) {
  const int qt = blockIdx.x, h = blockIdx.y, b = blockIdx.z;
  const int tid = threadIdx.x, lane = tid & 63, wave = tid >> 6;  // wave 0..7
  const int q0 = qt * 128;

  __shared__ bf16 Qs[128 * 64];   // 16 KB
  __shared__ bf16 Ks[64 * 64];    // 8 KB
  __shared__ bf16 VTs[64 * 64];   // 8 KB
  __shared__ bf16 Ps[8][16 * 64]; // 16 KB

  float sb = attn_bias[lane];
#pragma unroll
  for (int off = 32; off >= 1; off >>= 1) sb += __shfl_xor(sb, off);

  const long bh = (long)(b * 16 + h);
  const bf16* Qg = Q + (bh * 1024 + q0) * 64;
  const bf16* Kgh = Kg + bh * 1024 * 64;
  const bf16* VTgh = VT + bh * 64 * 1024;
  const float* fr = frac + b * 1024;

  const int lrow = tid >> 3;                          // 0..63
  const int lcolS = (((tid & 7) ^ (lrow & 7)) * 8);
#pragma unroll
  for (int i = 0; i < 2; ++i)
    gll16(Qg + (long)(i * 64 + lrow) * 64 + lcolS, Qs + (i * 64 + wave * 8) * 64);

  float fi[4];
  {
    int rbase = q0 + wave * 16 + ((lane >> 4) << 2);
#pragma unroll
    for (int r = 0; r < 4; ++r) fi[r] = fr[rbase + r];
  }

  float mrow[4] = {-1e30f, -1e30f, -1e30f, -1e30f};
  float lrw[4] = {0.f, 0.f, 0.f, 0.f};
  f32x4 acco[4] = {};
  const float scale = 0.125f;

  for (int kv0 = 0; kv0 < 1024; kv0 += 64) {
    __syncthreads();
    gll16(Kgh + (long)(kv0 + lrow) * 64 + lcolS, Ks + (wave * 8) * 64);
    gll16(VTgh + (long)lrow * 1024 + kv0 + lcolS, VTs + (wave * 8) * 64);
    __syncthreads();

    f32x4 sacc[4] = {};
#pragma unroll
    for (int kk = 0; kk < 2; ++kk) {
      const int ac = kk * 32 + (lane >> 4) * 8;
      const int rq = wave * 16 + (lane & 15);
      bf16x8 aq = *(const bf16x8*)(Qs + rq * 64 + (ac ^ ((rq & 7) << 3)));
#pragma unroll
      for (int nf = 0; nf < 4; ++nf) {
        const int rk = nf * 16 + (lane & 15);
        bf16x8 bk_ = *(const bf16x8*)(Ks + rk * 64 + (ac ^ ((rk & 7) << 3)));
        sacc[nf] = __builtin_amdgcn_mfma_f32_16x16x32_bf16(aq, bk_, sacc[nf], 0, 0, 0);
      }
    }

    float fj[4];
#pragma unroll
    for (int nf = 0; nf < 4; ++nf) fj[nf] = fr[kv0 + nf * 16 + (lane & 15)];

    float sv[4][4];
#pragma unroll
    for (int nf = 0; nf < 4; ++nf)
#pragma unroll
      for (int r = 0; r < 4; ++r) {
        float fac = (fj[nf] - fi[r]) * __builtin_amdgcn_rcpf(fi[r] * fj[nf] + 1e-8f);
        sv[nf][r] = (sacc[nf][r] + fac * sb) * scale;
      }

#pragma unroll
    for (int r = 0; r < 4; ++r) {
      float mx = fmaxf(fmaxf(sv[0][r], sv[1][r]), fmaxf(sv[2][r], sv[3][r]));
#pragma unroll
      for (int mk = 8; mk >= 1; mk >>= 1) mx = fmaxf(mx, __shfl_xor(mx, mk));
      float mnew = fmaxf(mrow[r], mx);
      float corr = __expf(mrow[r] - mnew);
      float rs = 0.f;
      const int pr = ((lane >> 4) << 2) + r;
#pragma unroll
      for (int nf = 0; nf < 4; ++nf) {
        float p = __expf(sv[nf][r] - mnew);
        rs += p;
        int pc = nf * 16 + (lane & 15);
        Ps[wave][pr * 64 + (pc ^ ((pr & 7) << 3))] = f2bf(p);
      }
#pragma unroll
      for (int mk = 8; mk >= 1; mk >>= 1) rs += __shfl_xor(rs, mk);
      lrw[r] = lrw[r] * corr + rs;
      mrow[r] = mnew;
#pragma unroll
      for (int nf = 0; nf < 4; ++nf) acco[nf][r] *= corr;
    }

#pragma unroll
    for (int kk = 0; kk < 2; ++kk) {
      const int ac = kk * 32 + (lane >> 4) * 8;
      const int rp = lane & 15;
      bf16x8 ap = *(const bf16x8*)(Ps[wave] + rp * 64 + (ac ^ ((rp & 7) << 3)));
#pragma unroll
      for (int nf = 0; nf < 4; ++nf) {
        const int rv = nf * 16 + (lane & 15);
        bf16x8 bv_ = *(const bf16x8*)(VTs + rv * 64 + (ac ^ ((rv & 7) << 3)));
        acco[nf] = __builtin_amdgcn_mfma_f32_16x16x32_bf16(ap, bv_, acco[nf], 0, 0, 0);
      }
    }
  }

#pragma unroll
  for (int nf = 0; nf < 4; ++nf)
#pragma unroll
    for (int r = 0; r < 4; ++r) {
      int t = q0 + wave * 16 + ((lane >> 4) << 2) + r;
      int d = h * 64 + nf * 16 + (lane & 15);
      O[((long)b * 1024 + t) * 1024 + d] = f2bf(acco[nf][r] / lrw[r]);
    }
}

// ---------------- fused LN1 + gate ----------------

__global__ __launch_bounds__(256) void ln1_gate_kernel(
    const float* __restrict__ xres,
    const float* __restrict__ g, const float* __restrict__ beta,
    const float* __restrict__ gw, const float* __restrict__ gb,
    float* __restrict__ xf, bf16* __restrict__ xb, float* __restrict__ comb) {
  const int row = blockIdx.x, tid = threadIdx.x;
  const long base = (long)row * 1024;
  float4 v4 = ((const float4*)(xres + base))[tid];
  float a[4] = {v4.x, v4.y, v4.z, v4.w};
  float s = a[0] + a[1] + a[2] + a[3];
  float s2 = a[0] * a[0] + a[1] * a[1] + a[2] * a[2] + a[3] * a[3];
#pragma unroll
  for (int off = 32; off >= 1; off >>= 1) { s += __shfl_xor(s, off); s2 += __shfl_xor(s2, off); }
  __shared__ float red[8];
  __shared__ float redg[4][4];
  const int wave = tid >> 6, lane = tid & 63;
  if (lane == 0) { red[wave] = s; red[4 + wave] = s2; }
  __syncthreads();
  s = red[0] + red[1] + red[2] + red[3];
  s2 = red[4] + red[5] + red[6] + red[7];
  float mu = s * (1.f / 1024.f);
  float var = s2 * (1.f / 1024.f) - mu * mu;
  float rstd = rsqrtf(var + 1e-5f);
  int c = tid * 4;
  float p[4] = {0.f, 0.f, 0.f, 0.f};
#pragma unroll
  for (int j = 0; j < 4; ++j) {
    float xv = (a[j] - mu) * rstd * g[c + j] + beta[c + j];
    xf[base + c + j] = xv;
    xb[base + c + j] = f2bf(xv);
#pragma unroll
    for (int e = 0; e < 4; ++e) p[e] += xv * gw[(c + j) * 4 + e];
  }
#pragma unroll
  for (int off = 32; off >= 1; off >>= 1)
#pragma unroll
    for (int e = 0; e < 4; ++e) p[e] += __shfl_xor(p[e], off);
  if (lane == 0)
#pragma unroll
    for (int e = 0; e < 4; ++e) redg[wave][e] = p[e];
  __syncthreads();
  if (tid == 0) {
    float sc[4];
    for (int e = 0; e < 4; ++e)
      sc[e] = redg[0][e] + redg[1][e] + redg[2][e] + redg[3][e] + gb[e];
    float mx = fmaxf(fmaxf(sc[0], sc[1]), fmaxf(sc[2], sc[3]));
    float se[4], ssum = 0.f;
    for (int e = 0; e < 4; ++e) { se[e] = __expf(sc[e] - mx); ssum += se[e]; }
    for (int e = 0; e < 4; ++e) se[e] /= ssum;
    int i1 = 0;
    for (int e = 1; e < 4; ++e) if (se[e] > se[i1]) i1 = e;
    int i2 = -1;
    for (int e = 0; e < 4; ++e) { if (e == i1) continue; if (i2 < 0 || se[e] > se[i2]) i2 = e; }
    for (int e = 0; e < 4; ++e) comb[(long)row * 4 + e] = (e == i1 || e == i2) ? se[e] : 0.f;
  }
}

// LN2: out = LN(xf + sum_{j<4} ff4[row][j])
__global__ __launch_bounds__(256) void ln2_kernel(
    const float* __restrict__ xf, const bf16* __restrict__ ff4,
    const float* __restrict__ g, const float* __restrict__ beta,
    float* __restrict__ out) {
  const int row = blockIdx.x, tid = threadIdx.x;
  const long base = (long)row * 1024;
  float4 v4 = ((const float4*)(xf + base))[tid];
  const bf16* frw = ff4 + (long)row * 4096;
  float a[4] = {v4.x, v4.y, v4.z, v4.w};
#pragma unroll
  for (int j = 0; j < 4; ++j) {
    ushort4 f = ((const ushort4*)(frw + j * 1024))[tid];
    a[0] += b2f(f.x); a[1] += b2f(f.y); a[2] += b2f(f.z); a[3] += b2f(f.w);
  }
  float s = a[0] + a[1] + a[2] + a[3];
  float s2 = a[0] * a[0] + a[1] * a[1] + a[2] * a[2] + a[3] * a[3];
#pragma unroll
  for (int off = 32; off >= 1; off >>= 1) { s += __shfl_xor(s, off); s2 += __shfl_xor(s2, off); }
  __shared__ float red[8];
  const int wave = tid >> 6, lane = tid & 63;
  if (lane == 0) { red[wave] = s; red[4 + wave] = s2; }
  __syncthreads();
  s = red[0] + red[1] + red[2] + red[3];
  s2 = red[4] + red[5] + red[6] + red[7];
  float mu = s * (1.f / 1024.f);
  float var = s2 * (1.f / 1024.f) - mu * mu;
  float rstd = rsqrtf(var + 1e-5f);
  int c = tid * 4;
#pragma unroll
  for (int j = 0; j < 4; ++j)
    out[base + c + j] = (a[j] - mu) * rstd * g[c + j] + beta[c + j];
}

// ---------------- MoE token compaction ----------------

__global__ __launch_bounds__(256) void compact_kernel(
    const float* __restrict__ comb, int* __restrict__ cnt, int* __restrict__ list) {
  int t = blockIdx.x * 256 + threadIdx.x;
  int slot = 0;
#pragma unroll
  for (int e = 0; e < 4; ++e) {
    float c = comb[(long)t * 4 + e];
    if (c != 0.f) {
      int pos = atomicAdd(&cnt[e], 1);
      list[e * 4096 + pos] = t | (slot << 12);
      slot++;
    }
  }
}

// ---------------- launch ----------------

extern "C" void kernel_launch(void* const* d_in, const int* in_sizes, int n_in,
                              void* d_out, int out_size, void* d_ws, size_t ws_size,
                              hipStream_t stream) {
  (void)in_sizes; (void)n_in; (void)out_size; (void)ws_size;
  const float* src = (const float*)d_in[0];
  const float* frac = (const float*)d_in[1];
  const float* Wq = (const float*)d_in[2];
  const float* bq = (const float*)d_in[3];
  const float* Wk = (const float*)d_in[4];
  const float* bk = (const float*)d_in[5];
  const float* Wv = (const float*)d_in[6];
  const float* bv = (const float*)d_in[7];
  const float* attn_bias = (const float*)d_in[8];
  const float* Wo = (const float*)d_in[9];
  const float* bo = (const float*)d_in[10];
  const float* gate_w = (const float*)d_in[11];
  const float* gate_b = (const float*)d_in[12];
  const float* ew1 = (const float*)d_in[13];
  const float* eb1 = (const float*)d_in[14];
  const float* ew2 = (const float*)d_in[15];
  const float* eb2 = (const float*)d_in[16];
  const float* ln1_g = (const float*)d_in[17];
  const float* ln1_b = (const float*)d_in[18];
  const float* ln2_g = (const float*)d_in[19];
  const float* ln2_b = (const float*)d_in[20];
  float* out = (float*)d_out;

  char* ws = (char*)d_ws;
  bf16* XB    = (bf16*)(ws + 0);                    // 8 MB: src bf16, later x bf16
  bf16* WQKVT = (bf16*)(ws + ((size_t)8 << 20));    // 6 MB
  bf16* WOT   = (bf16*)(ws + ((size_t)14 << 20));   // 2 MB
  bf16* EW1T  = (bf16*)(ws + ((size_t)16 << 20));   // 32 MB
  bf16* EW2T  = (bf16*)(ws + ((size_t)48 << 20));   // 32 MB
  bf16* QB    = (bf16*)(ws + ((size_t)80 << 20));   // 8 MB  (QB..AOB reused as FF4 after wo)
  bf16* KB    = (bf16*)(ws + ((size_t)88 << 20));   // 8 MB
  bf16* VTB   = (bf16*)(ws + ((size_t)96 << 20));   // 8 MB
  bf16* AOB   = (bf16*)(ws + ((size_t)104 << 20));  // 8 MB
  bf16* FF4   = QB;                                 // [4096][4][1024] bf16 = 32 MB
  float* XRES = (float*)(ws + ((size_t)112 << 20)); // 16 MB
  float* XF   = (float*)(ws + ((size_t)128 << 20)); // 16 MB
  float* COMB = (float*)(ws + ((size_t)144 << 20)); // 64 KB
  int*   LIST = (int*)(ws + ((size_t)144 << 20) + (64 << 10)); // 64 KB
  int*   CNT  = (int*)(ws + ((size_t)144 << 20) + (128 << 10)); // 16 B
  int*   TOT  = CNT + 8;
  int*   TILE = CNT + 16;                           // 128 ints
  bf16*  HALL = (bf16*)(ws + ((size_t)146 << 20));  // 8704 rows x 4096 = ~71.3 MB

  dim3 tb(32, 8);
  cast_bf16_kernel<<<4096, 256, 0, stream>>>(src, XB, (4 * 1024 * 1024) / 4);
  w_qkvo_kernel<<<dim3(1024, 4), tb, 0, stream>>>(Wq, Wk, Wv, Wo, WQKVT, WOT);
  w_experts_kernel<<<dim3(4096, 8), tb, 0, stream>>>(ew1, ew2, EW1T, EW2T);

  gemm_qkv_kernel<<<dim3(24, 32), 512, 0, stream>>>(XB, WQKVT, bq, bk, bv, QB, KB, VTB);
  attn_kernel<<<dim3(8, 16, 4), 512, 0, stream>>>(QB, KB, VTB, frac, attn_bias, AOB);
  gemm_wo_kernel<<<dim3(8, 32), 512, 0, stream>>>(AOB, WOT, bo, src, XRES);
  ln1_gate_kernel<<<4096, 256, 0, stream>>>(XRES, ln1_g, ln1_b, gate_w, gate_b, XF, XB, COMB);
  (void)hipMemsetAsync(CNT, 0, 4 * sizeof(int), stream);
  compact_kernel<<<16, 256, 0, stream>>>(COMB, CNT, LIST);

  tiles_kernel<<<1, 64, 0, stream>>>(CNT, TILE, TOT);
  ffn1_all_kernel<<<dim3(32, 72), 512, 0, stream>>>(XB, EW1T, eb1, LIST, CNT, TILE, TOT, HALL);
  ffn2_all_kernel<<<dim3(16, 68), 512, 0, stream>>>(HALL, EW2T, eb2, COMB, LIST, CNT, TILE, TOT, FF4);
  ln2_kernel<<<4096, 256, 0, stream>>>(XF, FF4, ln2_g, ln2_b, out);
}

// Round 23
// 426.430 us; speedup vs baseline: 1.0317x; 1.0007x over previous
//
#include <hip/hip_runtime.h>
#include <hip/hip_bf16.h>
#include <stdint.h>

typedef __hip_bfloat16 bf16;
typedef __attribute__((ext_vector_type(8))) short bf16x8;
typedef __attribute__((ext_vector_type(4))) float f32x4;

#define DEVFN static __device__ __forceinline__

DEVFN void gll16(const bf16* g, bf16* l) {
  __builtin_amdgcn_global_load_lds((const __attribute__((address_space(1))) void*)g,
                                   (__attribute__((address_space(3))) void*)l, 16, 0, 0);
}

DEVFN bf16 f2bf(float f) { return __float2bfloat16(f); }
DEVFN float b2f(unsigned short u) { return __bfloat162float(__builtin_bit_cast(bf16, u)); }

// ---------------- cast / transpose ----------------

__global__ __launch_bounds__(256) void cast_bf16_kernel(const float* __restrict__ in,
                                                        bf16* __restrict__ out, int n4) {
  int i = blockIdx.x * 256 + threadIdx.x;
  if (i >= n4) return;
  float4 v = ((const float4*)in)[i];
  ushort4 o;
  o.x = __builtin_bit_cast(unsigned short, f2bf(v.x));
  o.y = __builtin_bit_cast(unsigned short, f2bf(v.y));
  o.z = __builtin_bit_cast(unsigned short, f2bf(v.z));
  o.w = __builtin_bit_cast(unsigned short, f2bf(v.w));
  ((ushort4*)out)[i] = o;
}

DEVFN void tile_transpose(const float* __restrict__ in, bf16* __restrict__ out,
                          int R, int C, int r0, int c0) {
  __shared__ bf16 tile[32][33];
  for (int i = threadIdx.y; i < 32; i += 8)
    tile[i][threadIdx.x] = f2bf(in[(long)(r0 + i) * C + (c0 + threadIdx.x)]);
  __syncthreads();
  for (int i = threadIdx.y; i < 32; i += 8)
    out[(long)(c0 + i) * R + (r0 + threadIdx.x)] = tile[threadIdx.x][i];
}

// All 8 expert weight mats in one launch: z = e*2 + {0:ew1, 1:ew2}; 4096 tiles each.
__global__ __launch_bounds__(256) void w_experts_kernel(
    const float* __restrict__ ew1, const float* __restrict__ ew2,
    bf16* __restrict__ EW1T, bf16* __restrict__ EW2T) {
  const int z = blockIdx.y, e = z >> 1;
  const float* in;
  bf16* out;
  int R, C, TC;
  if ((z & 1) == 0) { in = ew1 + (long)e * 1024 * 4096; out = EW1T + (long)e * 4096 * 1024; R = 1024; C = 4096; TC = 128; }
  else              { in = ew2 + (long)e * 4096 * 1024; out = EW2T + (long)e * 1024 * 4096; R = 4096; C = 1024; TC = 32; }
  int flat = blockIdx.x;
  int tr = flat / TC, tc = flat - tr * TC;
  tile_transpose(in, out, R, C, tr * 32, tc * 32);
}

// Wq/Wk/Wv/Wo (all 1024x1024) in one launch: z picks matrix; 1024 tiles each.
__global__ __launch_bounds__(256) void w_qkvo_kernel(
    const float* __restrict__ Wq, const float* __restrict__ Wk,
    const float* __restrict__ Wv, const float* __restrict__ Wo,
    bf16* __restrict__ WQKVT, bf16* __restrict__ WOT) {
  const int z = blockIdx.y;
  const float* in = z == 0 ? Wq : z == 1 ? Wk : z == 2 ? Wv : Wo;
  bf16* out = z == 3 ? WOT : WQKVT + (long)z * 1024 * 1024;
  int flat = blockIdx.x;
  int tr = flat >> 5, tc = flat & 31;
  tile_transpose(in, out, 1024, 1024, tr * 32, tc * 32);
}

// ---------------- GEMM core (8-wave, 512 thr, single-buffer, BK=64) ----------------
// C(128x128) = A * Bt^T. Wave grid 4(M)x2(N); wave tile 32x64 -> acc[2][4]
// = 32 AGPRs/wave. XOR-swizzle both sides. STRUCTURAL NOTES: dbuf regressed
// twice (R11/R13) and BK=128 regressed (R19) — 64KB-LDS variants drop
// residency below TLP break-even; this 32KB core is the 2-barrier plateau.
// T5 setprio around the MFMA cluster: with ~2 independent blocks/CU at
// different K-phases, prefer MFMA-issuing waves over staging waves (the
// attention-style regime where setprio paid, not the lockstep null case).

DEVFN void gemm_core_ptr8(const bf16* const* aptr, const bf16* __restrict__ Bt,
                          int K, int ldb, int n0, f32x4 acc[2][4]) {
  __shared__ bf16 As[128 * 64];
  __shared__ bf16 Bs[128 * 64];
  const int tid = threadIdx.x;
  const int lane = tid & 63, wave = tid >> 6;        // 0..7
  const int wm = wave >> 1, wn = wave & 1;           // wm 0..3, wn 0..1
  const int lrow = tid >> 3;                         // 0..63
  const int lcolS = ((tid & 7) ^ (lrow & 7)) << 3;

  for (int k0 = 0; k0 < K; k0 += 64) {
    __syncthreads();
#pragma unroll
    for (int i = 0; i < 2; ++i) {
      gll16(aptr[i] + k0, As + (i * 64 + wave * 8) * 64);
      gll16(Bt + (long)(n0 + i * 64 + lrow) * ldb + (k0 + lcolS), Bs + (i * 64 + wave * 8) * 64);
    }
    __syncthreads();
    __builtin_amdgcn_s_setprio(1);
#pragma unroll
    for (int kk = 0; kk < 2; ++kk) {
      const int ac = kk * 32 + (lane >> 4) * 8;
      bf16x8 af[2], bb[4];
#pragma unroll
      for (int x = 0; x < 2; ++x) {
        const int ra = wm * 32 + (lane & 15) + x * 16;
        af[x] = *(const bf16x8*)(As + ra * 64 + (ac ^ ((ra & 7) << 3)));
      }
#pragma unroll
      for (int x = 0; x < 4; ++x) {
        const int rb = wn * 64 + (lane & 15) + x * 16;
        bb[x] = *(const bf16x8*)(Bs + rb * 64 + (ac ^ ((rb & 7) << 3)));
      }
#pragma unroll
      for (int mf = 0; mf < 2; ++mf)
#pragma unroll
        for (int nf = 0; nf < 4; ++nf)
          acc[mf][nf] = __builtin_amdgcn_mfma_f32_16x16x32_bf16(af[mf], bb[nf], acc[mf][nf], 0, 0, 0);
    }
    __builtin_amdgcn_s_setprio(0);
  }
}

// Contiguous-A wrapper for the 8-wave core.
DEVFN void gemm_core_128_8(const bf16* __restrict__ A, const bf16* __restrict__ Bt,
                           int K, int lda, int ldb, int m0, int n0, f32x4 acc[2][4]) {
  const int tid = threadIdx.x;
  const int lrow = tid >> 3;
  const int lcolS = ((tid & 7) ^ (lrow & 7)) << 3;
  const bf16* aptr[2];
#pragma unroll
  for (int i = 0; i < 2; ++i) aptr[i] = A + (long)(m0 + i * 64 + lrow) * lda + lcolS;
  gemm_core_ptr8(aptr, Bt, K, ldb, n0, acc);
}

// XCD-aware bijective swizzle of the flat block id (grid total % 8 == 0).
DEVFN int xcd_flat() {
  int flat = blockIdx.y * gridDim.x + blockIdx.x;
  int total = gridDim.x * gridDim.y;
  int q = total >> 3;
  return (flat & 7) * q + (flat >> 3);
}

#define EPILOGUE_VARS8                                       \
  const int lane = threadIdx.x & 63, wave = threadIdx.x >> 6; \
  const int wm = wave >> 1, wn = wave & 1;

// ---------------- GEMM kernels (all 8-wave) ----------------

__global__ __launch_bounds__(512, 4) void gemm_qkv_kernel(
    const bf16* __restrict__ X, const bf16* __restrict__ Wt,
    const float* __restrict__ bq, const float* __restrict__ bk, const float* __restrict__ bv,
    bf16* __restrict__ Q, bf16* __restrict__ Kb, bf16* __restrict__ VT) {
  const int m0 = blockIdx.y * 128, n0 = blockIdx.x * 128;
  f32x4 acc[2][4] = {};
  gemm_core_128_8(X, Wt, 1024, 1024, 1024, m0, n0, acc);
  EPILOGUE_VARS8
#pragma unroll
  for (int mf = 0; mf < 2; ++mf)
#pragma unroll
    for (int nf = 0; nf < 4; ++nf)
#pragma unroll
      for (int r = 0; r < 4; ++r) {
        int m = m0 + wm * 32 + mf * 16 + ((lane >> 4) << 2) + r;
        int n = n0 + wn * 64 + nf * 16 + (lane & 15);
        int b = m >> 10, t = m & 1023;
        float v = acc[mf][nf][r];
        if (n < 1024) {
          int h = n >> 6, hd = n & 63;
          Q[((long)(b * 16 + h) * 1024 + t) * 64 + hd] = f2bf(v + bq[n]);
        } else if (n < 2048) {
          int nn = n - 1024, h = nn >> 6, hd = nn & 63;
          Kb[((long)(b * 16 + h) * 1024 + t) * 64 + hd] = f2bf(v + bk[nn]);
        } else {
          int nn = n - 2048, h = nn >> 6, hd = nn & 63;
          VT[((long)(b * 16 + h) * 64 + hd) * 1024 + t] = f2bf(v + bv[nn]);
        }
      }
}

__global__ __launch_bounds__(512, 4) void gemm_wo_kernel(
    const bf16* __restrict__ AO, const bf16* __restrict__ Wot,
    const float* __restrict__ bo, const float* __restrict__ src,
    float* __restrict__ xres) {
  const int m0 = blockIdx.y * 128, n0 = blockIdx.x * 128;
  f32x4 acc[2][4] = {};
  gemm_core_128_8(AO, Wot, 1024, 1024, 1024, m0, n0, acc);
  EPILOGUE_VARS8
#pragma unroll
  for (int mf = 0; mf < 2; ++mf)
#pragma unroll
    for (int nf = 0; nf < 4; ++nf)
#pragma unroll
      for (int r = 0; r < 4; ++r) {
        int m = m0 + wm * 32 + mf * 16 + ((lane >> 4) << 2) + r;
        int n = n0 + wn * 64 + nf * 16 + (lane & 15);
        long idx = (long)m * 1024 + n;
        xres[idx] = acc[mf][nf][r] + bo[n] + src[idx];
      }
}

// ---------------- MoE: tile table + combined-expert FFN (8-wave) ----------------
// tbl[gt] = (e<<8) | local_tile_idx.  H rows for tile gt live at gt*128.

__global__ void tiles_kernel(const int* __restrict__ cnt, int* __restrict__ tbl,
                             int* __restrict__ tot) {
  if (threadIdx.x != 0 || blockIdx.x != 0) return;
  int acc = 0;
  for (int e = 0; e < 4; ++e) {
    int t = (cnt[e] + 127) >> 7;
    for (int i = 0; i < t; ++i) tbl[acc + i] = (e << 8) | i;
    acc += t;
  }
  *tot = acc;
}

// ffn1 block-order: 2-D grouped mapping (R18: dropped ffn1 out of top-5).
__global__ __launch_bounds__(512, 4) void ffn1_all_kernel(
    const bf16* __restrict__ X, const bf16* __restrict__ EW1T, const float* __restrict__ eb1,
    const int* __restrict__ list, const int* __restrict__ cnt,
    const int* __restrict__ tbl, const int* __restrict__ tot,
    bf16* __restrict__ H) {
  int swz = xcd_flat();                 // grid 32 x 72 = 2304
  int gtg = swz >> 8;                   // 0..8
  int rem = swz & 255;
  int nb = rem >> 3, gti = rem & 7;
  int gt = gtg * 8 + gti;
  if (gt >= *tot) return;
  const int ent = tbl[gt];
  const int e = ent >> 8, lti = ent & 255;
  const int nc = cnt[e];
  const int tid = threadIdx.x;
  const int lrow = tid >> 3;                        // 0..63
  const int lcolS = ((tid & 7) ^ (lrow & 7)) << 3;
  const bf16* aptr[2];
#pragma unroll
  for (int i = 0; i < 2; ++i) {
    int lm = lti * 128 + i * 64 + lrow;
    int pk = list[e * 4096 + (lm < nc ? lm : nc - 1)];
    aptr[i] = X + (long)(pk & 0xFFF) * 1024 + lcolS;
  }
  f32x4 acc[2][4] = {};
  gemm_core_ptr8(aptr, EW1T + (long)e * 4096 * 1024, 1024, 1024, nb * 128, acc);
  EPILOGUE_VARS8
  const int hbase = gt * 128;
#pragma unroll
  for (int mf = 0; mf < 2; ++mf)
#pragma unroll
    for (int nf = 0; nf < 4; ++nf)
#pragma unroll
      for (int r = 0; r < 4; ++r) {
        int ml = wm * 32 + mf * 16 + ((lane >> 4) << 2) + r;
        int n = nb * 128 + wn * 64 + nf * 16 + (lane & 15);
        float v = acc[mf][nf][r] + eb1[e * 4096 + n];
        H[(long)(hbase + ml) * 4096 + n] = f2bf(v > 0.f ? v : 0.f);
      }
}

// FFN2 split-K=2: x dim encodes (ks, nb); partials -> ff4[token][slot*2+ks][1024].
// BK=64 core (BK=128 regressed in R19: 64KB LDS -> occupancy 41->30%).
__global__ __launch_bounds__(512, 4) void ffn2_all_kernel(
    const bf16* __restrict__ H, const bf16* __restrict__ EW2T,
    const float* __restrict__ eb2, const float* __restrict__ comb,
    const int* __restrict__ list, const int* __restrict__ cnt,
    const int* __restrict__ tbl, const int* __restrict__ tot,
    bf16* __restrict__ ff4) {
  int swz = xcd_flat();
  int gt = swz >> 4;
  int xk = swz & 15;
  int nb = xk & 7, ks = xk >> 3;
  if (gt >= *tot) return;
  const int ent = tbl[gt];
  const int e = ent >> 8, lti = ent & 255;
  const int nc = cnt[e];
  const int tid = threadIdx.x;
  const int lrow = tid >> 3;
  const int lcolS = ((tid & 7) ^ (lrow & 7)) << 3;
  const bf16* Abase = H + (long)gt * 128 * 4096 + ks * 2048;
  const bf16* aptr[2];
#pragma unroll
  for (int i = 0; i < 2; ++i) aptr[i] = Abase + (long)(i * 64 + lrow) * 4096 + lcolS;
  f32x4 acc[2][4] = {};
  gemm_core_ptr8(aptr, EW2T + (long)e * 1024 * 4096 + ks * 2048, 2048, 4096, nb * 128, acc);
  EPILOGUE_VARS8
#pragma unroll
  for (int mf = 0; mf < 2; ++mf)
#pragma unroll
    for (int nf = 0; nf < 4; ++nf)
#pragma unroll
      for (int r = 0; r < 4; ++r) {
        int ml = wm * 32 + mf * 16 + ((lane >> 4) << 2) + r;
        int lm = lti * 128 + ml;
        if (lm < nc) {
          int pk = list[e * 4096 + lm];
          int t = pk & 0xFFF, slot = (pk >> 12) & 1;
          int n = nb * 128 + wn * 64 + nf * 16 + (lane & 15);
          float c = comb[(long)t * 4 + e];
          float v = acc[mf][nf][r] + (ks == 0 ? eb2[e * 1024 + n] : 0.f);
          ff4[((long)t * 4 + slot * 2 + ks) * 1024 + n] = f2bf(c * v);
        }
      }
}

// ---------------- attention (8-wave, Q-tile 128) ----------------

__global__ __launch_bounds__(512, 4) void attn_kernel(
    const bf16* __restrict__ Q, const bf16* __restrict__ Kg, const bf16* __restrict__ VT,
    const float* __restrict__ frac, const float* __restrict__ attn_bias,
    bf16* __restrict__ O) {
  const int qt = blockIdx.x, h = blockIdx.y, b = blockIdx.z;
  const int tid = threadIdx.x, lane = tid & 63, wave = tid >> 6;  // wave 0..7
  const int q0 = qt * 128;

  __shared__ bf16 Qs[128 * 64];   // 16 KB
  __shared__ bf16 Ks[64 * 64];    // 8 KB
  __shared__ bf16 VTs[64 * 64];   // 8 KB
  __shared__ bf16 Ps[8][16 * 64]; // 16 KB

  float sb = attn_bias[lane];
#pragma unroll
  for (int off = 32; off >= 1; off >>= 1) sb += __shfl_xor(sb, off);

  const long bh = (long)(b * 16 + h);
  const bf16* Qg = Q + (bh * 1024 + q0) * 64;
  const bf16* Kgh = Kg + bh * 1024 * 64;
  const bf16* VTgh = VT + bh * 64 * 1024;
  const float* fr = frac + b * 1024;

  const int lrow = tid >> 3;                          // 0..63
  const int lcolS = (((tid & 7) ^ (lrow & 7)) * 8);
#pragma unroll
  for (int i = 0; i < 2; ++i)
    gll16(Qg + (long)(i * 64 + lrow) * 64 + lcolS, Qs + (i * 64 + wave * 8) * 64);

  float fi[4];
  {
    int rbase = q0 + wave * 16 + ((lane >> 4) << 2);
#pragma unroll
    for (int r = 0; r < 4; ++r) fi[r] = fr[rbase + r];
  }

  float mrow[4] = {-1e30f, -1e30f, -1e30f, -1e30f};
  float lrw[4] = {0.f, 0.f, 0.f, 0.f};
  f32x4 acco[4] = {};
  const float scale = 0.125f;

  for (int kv0 = 0; kv0 < 1024; kv0 += 64) {
    __syncthreads();
    gll16(Kgh + (long)(kv0 + lrow) * 64 + lcolS, Ks + (wave * 8) * 64);
    gll16(VTgh + (long)lrow * 1024 + kv0 + lcolS, VTs + (wave * 8) * 64);
    __syncthreads();

    f32x4 sacc[4] = {};
#pragma unroll
    for (int kk = 0; kk < 2; ++kk) {
      const int ac = kk * 32 + (lane >> 4) * 8;
      const int rq = wave * 16 + (lane & 15);
      bf16x8 aq = *(const bf16x8*)(Qs + rq * 64 + (ac ^ ((rq & 7) << 3)));
#pragma unroll
      for (int nf = 0; nf < 4; ++nf) {
        const int rk = nf * 16 + (lane & 15);
        bf16x8 bk_ = *(const bf16x8*)(Ks + rk * 64 + (ac ^ ((rk & 7) << 3)));
        sacc[nf] = __builtin_amdgcn_mfma_f32_16x16x32_bf16(aq, bk_, sacc[nf], 0, 0, 0);
      }
    }

    float fj[4];
#pragma unroll
    for (int nf = 0; nf < 4; ++nf) fj[nf] = fr[kv0 + nf * 16 + (lane & 15)];

    float sv[4][4];
#pragma unroll
    for (int nf = 0; nf < 4; ++nf)
#pragma unroll
      for (int r = 0; r < 4; ++r) {
        float fac = (fj[nf] - fi[r]) * __builtin_amdgcn_rcpf(fi[r] * fj[nf] + 1e-8f);
        sv[nf][r] = (sacc[nf][r] + fac * sb) * scale;
      }

#pragma unroll
    for (int r = 0; r < 4; ++r) {
      float mx = fmaxf(fmaxf(sv[0][r], sv[1][r]), fmaxf(sv[2][r], sv[3][r]));
#pragma unroll
      for (int mk = 8; mk >= 1; mk >>= 1) mx = fmaxf(mx, __shfl_xor(mx, mk));
      float mnew = fmaxf(mrow[r], mx);
      float corr = __expf(mrow[r] - mnew);
      float rs = 0.f;
      const int pr = ((lane >> 4) << 2) + r;
#pragma unroll
      for (int nf = 0; nf < 4; ++nf) {
        float p = __expf(sv[nf][r] - mnew);
        rs += p;
        int pc = nf * 16 + (lane & 15);
        Ps[wave][pr * 64 + (pc ^ ((pr & 7) << 3))] = f2bf(p);
      }
#pragma unroll
      for (int mk = 8; mk >= 1; mk >>= 1) rs += __shfl_xor(rs, mk);
      lrw[r] = lrw[r] * corr + rs;
      mrow[r] = mnew;
#pragma unroll
      for (int nf = 0; nf < 4; ++nf) acco[nf][r] *= corr;
    }

#pragma unroll
    for (int kk = 0; kk < 2; ++kk) {
      const int ac = kk * 32 + (lane >> 4) * 8;
      const int rp = lane & 15;
      bf16x8 ap = *(const bf16x8*)(Ps[wave] + rp * 64 + (ac ^ ((rp & 7) << 3)));
#pragma unroll
      for (int nf = 0; nf < 4; ++nf) {
        const int rv = nf * 16 + (lane & 15);
        bf16x8 bv_ = *(const bf16x8*)(VTs + rv * 64 + (ac ^ ((rv & 7) << 3)));
        acco[nf] = __builtin_amdgcn_mfma_f32_16x16x32_bf16(ap, bv_, acco[nf], 0, 0, 0);
      }
    }
  }

#pragma unroll
  for (int nf = 0; nf < 4; ++nf)
#pragma unroll
    for (int r = 0; r < 4; ++r) {
      int t = q0 + wave * 16 + ((lane >> 4) << 2) + r;
      int d = h * 64 + nf * 16 + (lane & 15);
      O[((long)b * 1024 + t) * 1024 + d] = f2bf(acco[nf][r] / lrw[r]);
    }
}

// ---------------- fused LN1 + gate ----------------

__global__ __launch_bounds__(256) void ln1_gate_kernel(
    const float* __restrict__ xres,
    const float* __restrict__ g, const float* __restrict__ beta,
    const float* __restrict__ gw, const float* __restrict__ gb,
    float* __restrict__ xf, bf16* __restrict__ xb, float* __restrict__ comb) {
  const int row = blockIdx.x, tid = threadIdx.x;
  const long base = (long)row * 1024;
  float4 v4 = ((const float4*)(xres + base))[tid];
  float a[4] = {v4.x, v4.y, v4.z, v4.w};
  float s = a[0] + a[1] + a[2] + a[3];
  float s2 = a[0] * a[0] + a[1] * a[1] + a[2] * a[2] + a[3] * a[3];
#pragma unroll
  for (int off = 32; off >= 1; off >>= 1) { s += __shfl_xor(s, off); s2 += __shfl_xor(s2, off); }
  __shared__ float red[8];
  __shared__ float redg[4][4];
  const int wave = tid >> 6, lane = tid & 63;
  if (lane == 0) { red[wave] = s; red[4 + wave] = s2; }
  __syncthreads();
  s = red[0] + red[1] + red[2] + red[3];
  s2 = red[4] + red[5] + red[6] + red[7];
  float mu = s * (1.f / 1024.f);
  float var = s2 * (1.f / 1024.f) - mu * mu;
  float rstd = rsqrtf(var + 1e-5f);
  int c = tid * 4;
  float p[4] = {0.f, 0.f, 0.f, 0.f};
#pragma unroll
  for (int j = 0; j < 4; ++j) {
    float xv = (a[j] - mu) * rstd * g[c + j] + beta[c + j];
    xf[base + c + j] = xv;
    xb[base + c + j] = f2bf(xv);
#pragma unroll
    for (int e = 0; e < 4; ++e) p[e] += xv * gw[(c + j) * 4 + e];
  }
#pragma unroll
  for (int off = 32; off >= 1; off >>= 1)
#pragma unroll
    for (int e = 0; e < 4; ++e) p[e] += __shfl_xor(p[e], off);
  if (lane == 0)
#pragma unroll
    for (int e = 0; e < 4; ++e) redg[wave][e] = p[e];
  __syncthreads();
  if (tid == 0) {
    float sc[4];
    for (int e = 0; e < 4; ++e)
      sc[e] = redg[0][e] + redg[1][e] + redg[2][e] + redg[3][e] + gb[e];
    float mx = fmaxf(fmaxf(sc[0], sc[1]), fmaxf(sc[2], sc[3]));
    float se[4], ssum = 0.f;
    for (int e = 0; e < 4; ++e) { se[e] = __expf(sc[e] - mx); ssum += se[e]; }
    for (int e = 0; e < 4; ++e) se[e] /= ssum;
    int i1 = 0;
    for (int e = 1; e < 4; ++e) if (se[e] > se[i1]) i1 = e;
    int i2 = -1;
    for (int e = 0; e < 4; ++e) { if (e == i1) continue; if (i2 < 0 || se[e] > se[i2]) i2 = e; }
    for (int e = 0; e < 4; ++e) comb[(long)row * 4 + e] = (e == i1 || e == i2) ? se[e] : 0.f;
  }
}

// LN2: out = LN(xf + sum_{j<4} ff4[row][j])
__global__ __launch_bounds__(256) void ln2_kernel(
    const float* __restrict__ xf, const bf16* __restrict__ ff4,
    const float* __restrict__ g, const float* __restrict__ beta,
    float* __restrict__ out) {
  const int row = blockIdx.x, tid = threadIdx.x;
  const long base = (long)row * 1024;
  float4 v4 = ((const float4*)(xf + base))[tid];
  const bf16* frw = ff4 + (long)row * 4096;
  float a[4] = {v4.x, v4.y, v4.z, v4.w};
#pragma unroll
  for (int j = 0; j < 4; ++j) {
    ushort4 f = ((const ushort4*)(frw + j * 1024))[tid];
    a[0] += b2f(f.x); a[1] += b2f(f.y); a[2] += b2f(f.z); a[3] += b2f(f.w);
  }
  float s = a[0] + a[1] + a[2] + a[3];
  float s2 = a[0] * a[0] + a[1] * a[1] + a[2] * a[2] + a[3] * a[3];
#pragma unroll
  for (int off = 32; off >= 1; off >>= 1) { s += __shfl_xor(s, off); s2 += __shfl_xor(s2, off); }
  __shared__ float red[8];
  const int wave = tid >> 6, lane = tid & 63;
  if (lane == 0) { red[wave] = s; red[4 + wave] = s2; }
  __syncthreads();
  s = red[0] + red[1] + red[2] + red[3];
  s2 = red[4] + red[5] + red[6] + red[7];
  float mu = s * (1.f / 1024.f);
  float var = s2 * (1.f / 1024.f) - mu * mu;
  float rstd = rsqrtf(var + 1e-5f);
  int c = tid * 4;
#pragma unroll
  for (int j = 0; j < 4; ++j)
    out[base + c + j] = (a[j] - mu) * rstd * g[c + j] + beta[c + j];
}

// ---------------- MoE token compaction ----------------

__global__ __launch_bounds__(256) void compact_kernel(
    const float* __restrict__ comb, int* __restrict__ cnt, int* __restrict__ list) {
  int t = blockIdx.x * 256 + threadIdx.x;
  int slot = 0;
#pragma unroll
  for (int e = 0; e < 4; ++e) {
    float c = comb[(long)t * 4 + e];
    if (c != 0.f) {
      int pos = atomicAdd(&cnt[e], 1);
      list[e * 4096 + pos] = t | (slot << 12);
      slot++;
    }
  }
}

// ---------------- launch ----------------

extern "C" void kernel_launch(void* const* d_in, const int* in_sizes, int n_in,
                              void* d_out, int out_size, void* d_ws, size_t ws_size,
                              hipStream_t stream) {
  (void)in_sizes; (void)n_in; (void)out_size; (void)ws_size;
  const float* src = (const float*)d_in[0];
  const float* frac = (const float*)d_in[1];
  const float* Wq = (const float*)d_in[2];
  const float* bq = (const float*)d_in[3];
  const float* Wk = (const float*)d_in[4];
  const float* bk = (const float*)d_in[5];
  const float* Wv = (const float*)d_in[6];
  const float* bv = (const float*)d_in[7];
  const float* attn_bias = (const float*)d_in[8];
  const float* Wo = (const float*)d_in[9];
  const float* bo = (const float*)d_in[10];
  const float* gate_w = (const float*)d_in[11];
  const float* gate_b = (const float*)d_in[12];
  const float* ew1 = (const float*)d_in[13];
  const float* eb1 = (const float*)d_in[14];
  const float* ew2 = (const float*)d_in[15];
  const float* eb2 = (const float*)d_in[16];
  const float* ln1_g = (const float*)d_in[17];
  const float* ln1_b = (const float*)d_in[18];
  const float* ln2_g = (const float*)d_in[19];
  const float* ln2_b = (const float*)d_in[20];
  float* out = (float*)d_out;

  char* ws = (char*)d_ws;
  bf16* XB    = (bf16*)(ws + 0);                    // 8 MB: src bf16, later x bf16
  bf16* WQKVT = (bf16*)(ws + ((size_t)8 << 20));    // 6 MB
  bf16* WOT   = (bf16*)(ws + ((size_t)14 << 20));   // 2 MB
  bf16* EW1T  = (bf16*)(ws + ((size_t)16 << 20));   // 32 MB
  bf16* EW2T  = (bf16*)(ws + ((size_t)48 << 20));   // 32 MB
  bf16* QB    = (bf16*)(ws + ((size_t)80 << 20));   // 8 MB  (QB..AOB reused as FF4 after wo)
  bf16* KB    = (bf16*)(ws + ((size_t)88 << 20));   // 8 MB
  bf16* VTB   = (bf16*)(ws + ((size_t)96 << 20));   // 8 MB
  bf16* AOB   = (bf16*)(ws + ((size_t)104 << 20));  // 8 MB
  bf16* FF4   = QB;                                 // [4096][4][1024] bf16 = 32 MB
  float* XRES = (float*)(ws + ((size_t)112 << 20)); // 16 MB
  float* XF   = (float*)(ws + ((size_t)128 << 20)); // 16 MB
  float* COMB = (float*)(ws + ((size_t)144 << 20)); // 64 KB
  int*   LIST = (int*)(ws + ((size_t)144 << 20) + (64 << 10)); // 64 KB
  int*   CNT  = (int*)(ws + ((size_t)144 << 20) + (128 << 10)); // 16 B
  int*   TOT  = CNT + 8;
  int*   TILE = CNT + 16;                           // 128 ints
  bf16*  HALL = (bf16*)(ws + ((size_t)146 << 20));  // 8704 rows x 4096 = ~71.3 MB

  dim3 tb(32, 8);
  cast_bf16_kernel<<<4096, 256, 0, stream>>>(src, XB, (4 * 1024 * 1024) / 4);
  w_qkvo_kernel<<<dim3(1024, 4), tb, 0, stream>>>(Wq, Wk, Wv, Wo, WQKVT, WOT);
  w_experts_kernel<<<dim3(4096, 8), tb, 0, stream>>>(ew1, ew2, EW1T, EW2T);

  gemm_qkv_kernel<<<dim3(24, 32), 512, 0, stream>>>(XB, WQKVT, bq, bk, bv, QB, KB, VTB);
  attn_kernel<<<dim3(8, 16, 4), 512, 0, stream>>>(QB, KB, VTB, frac, attn_bias, AOB);
  gemm_wo_kernel<<<dim3(8, 32), 512, 0, stream>>>(AOB, WOT, bo, src, XRES);
  ln1_gate_kernel<<<4096, 256, 0, stream>>>(XRES, ln1_g, ln1_b, gate_w, gate_b, XF, XB, COMB);
  (void)hipMemsetAsync(CNT, 0, 4 * sizeof(int), stream);
  compact_kernel<<<16, 256, 0, stream>>>(COMB, CNT, LIST);

  tiles_kernel<<<1, 64, 0, stream>>>(CNT, TILE, TOT);
  ffn1_all_kernel<<<dim3(32, 72), 512, 0, stream>>>(XB, EW1T, eb1, LIST, CNT, TILE, TOT, HALL);
  ffn2_all_kernel<<<dim3(16, 68), 512, 0, stream>>>(HALL, EW2T, eb2, COMB, LIST, CNT, TILE, TOT, FF4);
  ln2_kernel<<<4096, 256, 0, stream>>>(XF, FF4, ln2_g, ln2_b, out);
}